// Round 16
// baseline (222.833 us; speedup 1.0000x reference)
//
#include <hip/hip_runtime.h>
#include <hip/hip_bf16.h>

#define NN 8192
#define NFEAT 512
#define NHID 64
#define NCLASS 16
#define NHEAD 4
#define ALPHA 0.1f
#define CAP 768
#define ZSPLIT 8
#define JPB (NN / ZSPLIT)   // 1024 j per block

typedef short bf16x8 __attribute__((ext_vector_type(8)));
typedef float f32x4 __attribute__((ext_vector_type(4)));
typedef float fv4 __attribute__((ext_vector_type(4)));

__device__ __forceinline__ float lrelu(float x) { return fmaxf(x, ALPHA * x); }
__device__ __forceinline__ float elu(float x) { return x > 0.f ? x : __expf(x) - 1.f; }
__device__ __forceinline__ short f2b(float x) {
  union { __bf16 b; short s; } c; c.b = (__bf16)x; return c.s;
}
__device__ __forceinline__ float b2f(short x) {
  union { unsigned int u; float f; } c; c.u = ((unsigned int)(unsigned short)x) << 16; return c.f;
}

#define UPF(w, v, A0, A1)                                  \
  {                                                        \
    const float lo_ = __uint_as_float((v) << 16);          \
    const float hi_ = __uint_as_float((v) & 0xffff0000u);  \
    (A0) += (w) * lo_;                                     \
    (A1) += (w) * hi_;                                     \
  }

// ---------------- K0b: WB[h][d][k] = bf16(W[h][k][d]) ----------------
__global__ __launch_bounds__(256) void k_wprep(const float* __restrict__ W,
                                               short* __restrict__ WB) {
  __shared__ float t[64][65];
  const int h = blockIdx.y;
  const int k0 = blockIdx.x * 64;
  const int tid = threadIdx.x;
#pragma unroll
  for (int it = 0; it < 16; ++it) {
    const int r = it * 4 + (tid >> 6), c = tid & 63;
    t[r][c] = W[((size_t)h * NFEAT + k0 + r) * NHID + c];
  }
  __syncthreads();
#pragma unroll
  for (int it = 0; it < 16; ++it) {
    const int d = it * 4 + (tid >> 6), k = tid & 63;
    WB[((size_t)h * NHID + d) * NFEAT + k0 + k] = f2b(t[k][d]);
  }
}

// ---------------- K1: Wh = bf16(x) @ WB^T (MFMA); epilogue f1/f2 + Whf j-blocked ------
__global__ __launch_bounds__(256) void k_prep1(const float* __restrict__ x,
                                               const short* __restrict__ WB,
                                               const float* __restrict__ a,
                                               short* __restrict__ Whf,
                                               float* __restrict__ f1i,
                                               float* __restrict__ f2i) {
  __shared__ short tile[64][72];
  const int bid = blockIdx.x;
  const int h = bid >> 7;
  const int bm = (bid & 127) * 64;
  const int tid = threadIdx.x;
  const int wv = tid >> 6, lane = tid & 63;
  const int mr = lane & 15, kg = lane >> 4;
  f32x4 acc0 = {0.f, 0.f, 0.f, 0.f}, acc1 = acc0, acc2 = acc0, acc3 = acc0;
  const float* ap = x + (size_t)(bm + wv * 16 + mr) * NFEAT + kg * 8;
  const short* bp = WB + ((size_t)h * NHID + mr) * NFEAT + kg * 8;
#pragma unroll 2
  for (int k0 = 0; k0 < NFEAT; k0 += 32) {
    const float4 xa = *reinterpret_cast<const float4*>(ap);
    const float4 xb = *reinterpret_cast<const float4*>(ap + 4);
    bf16x8 af;
    af[0] = f2b(xa.x); af[1] = f2b(xa.y); af[2] = f2b(xa.z); af[3] = f2b(xa.w);
    af[4] = f2b(xb.x); af[5] = f2b(xb.y); af[6] = f2b(xb.z); af[7] = f2b(xb.w);
    const bf16x8 b0 = *reinterpret_cast<const bf16x8*>(bp);
    const bf16x8 b1 = *reinterpret_cast<const bf16x8*>(bp + 16 * NFEAT);
    const bf16x8 b2 = *reinterpret_cast<const bf16x8*>(bp + 32 * NFEAT);
    const bf16x8 b3 = *reinterpret_cast<const bf16x8*>(bp + 48 * NFEAT);
    acc0 = __builtin_amdgcn_mfma_f32_16x16x32_bf16(af, b0, acc0, 0, 0, 0);
    acc1 = __builtin_amdgcn_mfma_f32_16x16x32_bf16(af, b1, acc1, 0, 0, 0);
    acc2 = __builtin_amdgcn_mfma_f32_16x16x32_bf16(af, b2, acc2, 0, 0, 0);
    acc3 = __builtin_amdgcn_mfma_f32_16x16x32_bf16(af, b3, acc3, 0, 0, 0);
    ap += 32; bp += 32;
  }
  float a1v[4], a2v[4];
#pragma unroll
  for (int c = 0; c < 4; ++c) {
    a1v[c] = a[h * 128 + mr + c * 16];
    a2v[c] = a[h * 128 + 64 + mr + c * 16];
  }
#pragma unroll
  for (int q = 0; q < 4; ++q) {
    float s1 = acc0[q] * a1v[0] + acc1[q] * a1v[1] + acc2[q] * a1v[2] + acc3[q] * a1v[3];
    float s2 = acc0[q] * a2v[0] + acc1[q] * a2v[1] + acc2[q] * a2v[2] + acc3[q] * a2v[3];
#pragma unroll
    for (int off = 1; off < 16; off <<= 1) {
      s1 += __shfl_xor(s1, off);
      s2 += __shfl_xor(s2, off);
    }
    if (mr == 0) {
      const int i = bm + wv * 16 + kg * 4 + q;
      f1i[(size_t)i * 4 + h] = s1;
      f2i[(size_t)i * 4 + h] = s2;
    }
  }
#pragma unroll
  for (int q = 0; q < 4; ++q) {
    const int r = wv * 16 + kg * 4 + q;
    tile[r][mr +  0] = f2b(acc0[q]);
    tile[r][mr + 16] = f2b(acc1[q]);
    tile[r][mr + 32] = f2b(acc2[q]);
    tile[r][mr + 48] = f2b(acc3[q]);
  }
  __syncthreads();
#pragma unroll
  for (int it = 0; it < 2; ++it) {
    const int jbl = (tid >> 6) + it * 4;
    const int d = tid & 63;
    bf16x8 o;
#pragma unroll
    for (int jo = 0; jo < 8; ++jo) o[jo] = tile[jbl * 8 + jo][d];
    *reinterpret_cast<bf16x8*>(Whf +
        (((size_t)h * 1024 + (bm >> 3) + jbl) * 64 + d) * 8) = o;
  }
}

// ---------------- K2c: strided max reduce ----------------
__global__ __launch_bounds__(256) void k_rmax(const float* __restrict__ src,
                                              float* __restrict__ dst, int n, int stride,
                                              int boff) {
  const float* p = src + (size_t)blockIdx.x * boff;
  float m = -1e30f;
  for (int k = threadIdx.x; k < n; k += 256) m = fmaxf(m, p[(size_t)k * stride]);
#pragma unroll
  for (int off = 32; off; off >>= 1) m = fmaxf(m, __shfl_xor(m, off));
  __shared__ float sm[4];
  if ((threadIdx.x & 63) == 0) sm[threadIdx.x >> 6] = m;
  __syncthreads();
  if (threadIdx.x == 0) dst[blockIdx.x] = fmaxf(fmaxf(sm[0], sm[1]), fmaxf(sm[2], sm[3]));
}

// ---------------- K2d: per-node factor tables ----------------
__global__ __launch_bounds__(256) void k_acbd(const float* __restrict__ f1i,
                                              const float* __restrict__ f2i,
                                              const float* __restrict__ f2max,
                                              float2* __restrict__ ACh,
                                              unsigned int* __restrict__ BDh) {
  const int idx = blockIdx.x * 256 + threadIdx.x;
  const int i = idx & (NN - 1);
  const int h = idx >> 13;
  const float fm = f2max[h];
  const float f1 = f1i[(size_t)i * 4 + h];
  const float f2 = f2i[(size_t)i * 4 + h];
  const float s = f1 + fm;
  const float mrow = fmaxf(s, 0.1f * s);
  float2 ac;
  ac.x = __expf(s - mrow);
  ac.y = __expf(0.1f * s - mrow);
  ACh[(size_t)h * NN + i] = ac;
  const float t = f2 - fm;
  const unsigned int B = (unsigned short)f2b(__expf(t));
  const unsigned int D = (unsigned short)f2b(__expf(0.1f * t));
  BDh[(size_t)h * NN + i] = B | (D << 16);
}

// ---------------- K3: fused adj-scan + masked dense MFMA layer-1 (z-tiled) ----------------
// grid (128, ZSPLIT) = 1024 blocks (4/CU, whole grid resident).
// Block = 64 rows x 1024 j x 4 heads. Phase 1: adj tile -> LDS mask + global bmask.
// Phase 2: wave = head; K-outer / m-inner (B loaded once per 32-j step, shared by 4 m-tiles).
__global__ __launch_bounds__(256) void k_fuse1(const float* __restrict__ adj,
                                               const short* __restrict__ Whf,
                                               const float2* __restrict__ ACh,
                                               const unsigned int* __restrict__ BDh,
                                               float* __restrict__ OpP,
                                               float* __restrict__ rsP,
                                               unsigned int* __restrict__ bmask) {
  __shared__ unsigned int sm_mask[64][33];
  const int i0 = blockIdx.x * 64;
  const int z = blockIdx.y;
  const int jb0 = z * JPB;
  const int tid = threadIdx.x;

  // ---- phase 1: adj (64 x 1024) -> bitmask (2 rows per pass, coalesced fv4) ----
  {
    const int rr = tid >> 7;        // 0..1
    const int ct = tid & 127;       // 8 cols per thread
#pragma unroll 2
    for (int p = 0; p < 32; ++p) {
      const int row = p * 2 + rr;
      const fv4* rp = reinterpret_cast<const fv4*>(adj + (size_t)(i0 + row) * NN + jb0) + ct * 2;
      const fv4 v0 = __builtin_nontemporal_load(rp);
      const fv4 v1 = __builtin_nontemporal_load(rp + 1);
      unsigned int b = (unsigned int)(v0.x > 0.f) | ((unsigned int)(v0.y > 0.f) << 1) |
                       ((unsigned int)(v0.z > 0.f) << 2) | ((unsigned int)(v0.w > 0.f) << 3) |
                       ((unsigned int)(v1.x > 0.f) << 4) | ((unsigned int)(v1.y > 0.f) << 5) |
                       ((unsigned int)(v1.z > 0.f) << 6) | ((unsigned int)(v1.w > 0.f) << 7);
      unsigned int nv = b << ((tid & 3) * 8);
      nv |= __shfl_xor(nv, 1);
      nv |= __shfl_xor(nv, 2);
      if ((tid & 3) == 0) {
        const int wd = ct >> 2;     // 0..31
        sm_mask[row][wd] = nv;
        bmask[(size_t)(i0 + row) * 256 + (jb0 >> 5) + wd] = nv;
      }
    }
  }
  __syncthreads();

  // ---- phase 2: wave = head ----
  const int wv = tid >> 6, lane = tid & 63;
  const int mr = lane & 15, kg = lane >> 4;
  const int h = wv;
  float2 ac0 = ACh[(size_t)h * NN + i0 +  0 + mr];
  float2 ac1 = ACh[(size_t)h * NN + i0 + 16 + mr];
  float2 ac2 = ACh[(size_t)h * NN + i0 + 32 + mr];
  float2 ac3 = ACh[(size_t)h * NN + i0 + 48 + mr];
  f32x4 acc[4][4];
#pragma unroll
  for (int mt = 0; mt < 4; ++mt)
#pragma unroll
    for (int dq = 0; dq < 4; ++dq) acc[mt][dq] = (f32x4){0.f, 0.f, 0.f, 0.f};
  float rs0 = 0.f, rs1 = 0.f, rs2 = 0.f, rs3 = 0.f;
  const unsigned int* bdh = BDh + (size_t)h * NN + jb0;
  const short* whb = Whf + ((size_t)h * 1024 + (jb0 >> 3)) * 512 + mr * 8;

  for (int ks = 0; ks < 32; ++ks) {
    const int jl = ks * 32 + kg * 8;
    const uint4 bda = *reinterpret_cast<const uint4*>(bdh + jl);
    const uint4 bdb = *reinterpret_cast<const uint4*>(bdh + jl + 4);
    const short* wp = whb + (size_t)(jl >> 3) * 512;
    const bf16x8 bf0 = *reinterpret_cast<const bf16x8*>(wp);
    const bf16x8 bf1 = *reinterpret_cast<const bf16x8*>(wp + 128);
    const bf16x8 bf2 = *reinterpret_cast<const bf16x8*>(wp + 256);
    const bf16x8 bf3 = *reinterpret_cast<const bf16x8*>(wp + 384);
#define MKW(e, bdw, acv, rsv)                                    \
    {                                                            \
      const float Bf = __uint_as_float((bdw) << 16);             \
      const float Df = __uint_as_float((bdw) & 0xffff0000u);     \
      float w_ = fmaxf((acv).x * Bf, (acv).y * Df);              \
      w_ = ((mb >> (e)) & 1u) ? w_ : 0.f;                        \
      (rsv) += w_;                                               \
      af[e] = f2b(w_);                                           \
    }
#define DOMT(mt, acv, rsv)                                                        \
    {                                                                             \
      const unsigned int mb = (sm_mask[(mt) * 16 + mr][ks] >> (kg * 8)) & 0xffu;  \
      bf16x8 af;                                                                  \
      MKW(0, bda.x, acv, rsv) MKW(1, bda.y, acv, rsv)                             \
      MKW(2, bda.z, acv, rsv) MKW(3, bda.w, acv, rsv)                             \
      MKW(4, bdb.x, acv, rsv) MKW(5, bdb.y, acv, rsv)                             \
      MKW(6, bdb.z, acv, rsv) MKW(7, bdb.w, acv, rsv)                             \
      acc[mt][0] = __builtin_amdgcn_mfma_f32_16x16x32_bf16(af, bf0, acc[mt][0], 0, 0, 0); \
      acc[mt][1] = __builtin_amdgcn_mfma_f32_16x16x32_bf16(af, bf1, acc[mt][1], 0, 0, 0); \
      acc[mt][2] = __builtin_amdgcn_mfma_f32_16x16x32_bf16(af, bf2, acc[mt][2], 0, 0, 0); \
      acc[mt][3] = __builtin_amdgcn_mfma_f32_16x16x32_bf16(af, bf3, acc[mt][3], 0, 0, 0); \
    }
    DOMT(0, ac0, rs0)
    DOMT(1, ac1, rs1)
    DOMT(2, ac2, rs2)
    DOMT(3, ac3, rs3)
#undef DOMT
#undef MKW
  }
  rs0 += __shfl_xor(rs0, 16); rs0 += __shfl_xor(rs0, 32);
  rs1 += __shfl_xor(rs1, 16); rs1 += __shfl_xor(rs1, 32);
  rs2 += __shfl_xor(rs2, 16); rs2 += __shfl_xor(rs2, 32);
  rs3 += __shfl_xor(rs3, 16); rs3 += __shfl_xor(rs3, 32);
  float* rsp = rsP + ((size_t)z * NHEAD + h) * NN + i0;
  if (lane < 16) {
    rsp[ 0 + lane] = rs0;
    rsp[16 + lane] = rs1;
    rsp[32 + lane] = rs2;
    rsp[48 + lane] = rs3;
  }
  float* op = OpP + (((size_t)z * NHEAD + h) * NN + i0) * 64;
#pragma unroll
  for (int mt = 0; mt < 4; ++mt)
#pragma unroll
    for (int q = 0; q < 4; ++q) {
      const int r = mt * 16 + kg * 4 + q;
      op[(size_t)r * 64 + mr +  0] = acc[mt][0][q];
      op[(size_t)r * 64 + mr + 16] = acc[mt][1][q];
      op[(size_t)r * 64 + mr + 32] = acc[mt][2][q];
      op[(size_t)r * 64 + mr + 48] = acc[mt][3][q];
    }
}

// ---------------- K3c: combine z-partials -> hcat bf16 ----------------
__global__ __launch_bounds__(256) void k_comb1(const float* __restrict__ OpP,
                                               const float* __restrict__ rsP,
                                               short* __restrict__ hcat) {
  const int idx = blockIdx.x * 256 + threadIdx.x;
  const int i = idx >> 8;
  const int hc = idx & 255;
  const int h = hc >> 6, d = hc & 63;
  float s = 0.f, rsum = 0.f;
#pragma unroll
  for (int z = 0; z < ZSPLIT; ++z) {
    s += OpP[(((size_t)z * NHEAD + h) * NN + i) * 64 + d];
    rsum += rsP[((size_t)z * NHEAD + h) * NN + i];
  }
  hcat[idx] = f2b(elu(s / rsum));
}

// ---------------- K4: Wh2B = (hcat @ W_out) bf16 ; f1o/f2o ----------------
__global__ __launch_bounds__(256) void k_gemm2(const short* __restrict__ hcat,
                                               const float* __restrict__ Wout,
                                               const float* __restrict__ aout,
                                               short* __restrict__ Wh2B,
                                               float* __restrict__ f1o,
                                               float* __restrict__ f2o) {
  __shared__ float sW[NHEAD * NHID][NCLASS + 1];
  __shared__ float sh[16][NHEAD * NHID + 1];
  const int tid = threadIdx.x;
  const int r = tid >> 4, c = tid & 15;
  const int row = blockIdx.x * 16 + r;
  for (int u = tid; u < 256 * 16; u += 256) sW[u >> 4][u & 15] = Wout[u];
  for (int u = tid; u < 16 * 256; u += 256)
    sh[u >> 8][u & 255] = b2f(hcat[(size_t)(blockIdx.x * 16 + (u >> 8)) * 256 + (u & 255)]);
  __syncthreads();
  float acc = 0.f;
#pragma unroll 8
  for (int f = 0; f < 256; ++f) acc += sh[r][f] * sW[f][c];
  Wh2B[(size_t)row * NCLASS + c] = f2b(acc);
  float s1 = acc * aout[c];
  float s2 = acc * aout[NCLASS + c];
#pragma unroll
  for (int off = 8; off; off >>= 1) { s1 += __shfl_xor(s1, off); s2 += __shfl_xor(s2, off); }
  if (c == 0) { f1o[row] = s1; f2o[row] = s2; }
}

// ---------------- K5: layer-2 attention from bitmask + log_softmax ----------------
__global__ __launch_bounds__(256) void k_attn2(const unsigned int* __restrict__ bmask,
                                               const short* __restrict__ Wh2B,
                                               const float* __restrict__ f1o,
                                               const float* __restrict__ f2o,
                                               const float* __restrict__ f2omax,
                                               float* __restrict__ out) {
  __shared__ unsigned short idx[CAP];
  __shared__ unsigned int wj[CAP + 4];
  __shared__ float red[4][NCLASS];
  __shared__ float swp[4];
  __shared__ float sinvs;
  __shared__ int cnt;
  const int i = blockIdx.x;
  const int tid = threadIdx.x;
  const int wv = tid >> 6, lane = tid & 63;
  if (tid == 0) cnt = 0;
  __syncthreads();

  {
    unsigned int word = bmask[(size_t)i * 256 + tid];
    const int c = __popc(word);
    if (c) {
      int base = atomicAdd(&cnt, c);
      const int j0 = tid * 32;
      while (word) {
        const int b = __ffs(word) - 1;
        word &= word - 1;
        if (base < CAP) idx[base++] = (unsigned short)(j0 + b);
      }
    }
  }
  __syncthreads();
  const int n = min(cnt, CAP);
  if (tid < 4) wj[n + tid] = 0;

  const float f1r = f1o[i];
  const float mrow = lrelu(f1r + f2omax[0]);
  float sw = 0.f;
  for (int k = tid; k < n; k += 256) {
    const int j = idx[k];
    const float w = __expf(lrelu(f1r + f2o[j]) - mrow);
    wj[k] = ((unsigned int)(unsigned short)f2b(w) << 16) | (unsigned int)j;
    sw += w;
  }
#pragma unroll
  for (int off = 32; off; off >>= 1) sw += __shfl_xor(sw, off);
  if (lane == 0) swp[wv] = sw;
  __syncthreads();
  if (tid == 0) sinvs = 1.f / (swp[0] + swp[1] + swp[2] + swp[3]);
  __syncthreads();

  const int grp = tid >> 2, gl = tid & 3;
  float acc0 = 0.f, acc1 = 0.f, acc2 = 0.f, acc3 = 0.f;
  const short* wb = Wh2B + gl * 4;
  for (int kb = grp * 4; kb < n; kb += 256) {
    const uint4 pw = *reinterpret_cast<const uint4*>(wj + kb);
    const uint2 e0 = *reinterpret_cast<const uint2*>(wb + (size_t)(pw.x & 0xffffu) * NCLASS);
    const uint2 e1 = *reinterpret_cast<const uint2*>(wb + (size_t)(pw.y & 0xffffu) * NCLASS);
    const uint2 e2 = *reinterpret_cast<const uint2*>(wb + (size_t)(pw.z & 0xffffu) * NCLASS);
    const uint2 e3 = *reinterpret_cast<const uint2*>(wb + (size_t)(pw.w & 0xffffu) * NCLASS);
    const float w0 = __uint_as_float(pw.x & 0xffff0000u);
    const float w1 = __uint_as_float(pw.y & 0xffff0000u);
    const float w2 = __uint_as_float(pw.z & 0xffff0000u);
    const float w3 = __uint_as_float(pw.w & 0xffff0000u);
    UPF(w0, e0.x, acc0, acc1) UPF(w0, e0.y, acc2, acc3)
    UPF(w1, e1.x, acc0, acc1) UPF(w1, e1.y, acc2, acc3)
    UPF(w2, e2.x, acc0, acc1) UPF(w2, e2.y, acc2, acc3)
    UPF(w3, e3.x, acc0, acc1) UPF(w3, e3.y, acc2, acc3)
  }
  acc0 += __shfl_xor(acc0, 4);  acc1 += __shfl_xor(acc1, 4);
  acc2 += __shfl_xor(acc2, 4);  acc3 += __shfl_xor(acc3, 4);
  acc0 += __shfl_xor(acc0, 8);  acc1 += __shfl_xor(acc1, 8);
  acc2 += __shfl_xor(acc2, 8);  acc3 += __shfl_xor(acc3, 8);
  acc0 += __shfl_xor(acc0, 16); acc1 += __shfl_xor(acc1, 16);
  acc2 += __shfl_xor(acc2, 16); acc3 += __shfl_xor(acc3, 16);
  acc0 += __shfl_xor(acc0, 32); acc1 += __shfl_xor(acc1, 32);
  acc2 += __shfl_xor(acc2, 32); acc3 += __shfl_xor(acc3, 32);
  if (lane < 4) {
    red[wv][lane * 4 + 0] = acc0;
    red[wv][lane * 4 + 1] = acc1;
    red[wv][lane * 4 + 2] = acc2;
    red[wv][lane * 4 + 3] = acc3;
  }
  __syncthreads();
  if (tid < NCLASS) {
    const float s = red[0][tid] + red[1][tid] + red[2][tid] + red[3][tid];
    const float v = elu(s * sinvs);
    float vm = v;
#pragma unroll
    for (int off = 8; off; off >>= 1) vm = fmaxf(vm, __shfl_xor(vm, off, 16));
    float ex = __expf(v - vm);
#pragma unroll
    for (int off = 8; off; off >>= 1) ex += __shfl_xor(ex, off, 16);
    out[(size_t)i * NCLASS + tid] = v - vm - __logf(ex);
  }
}

extern "C" void kernel_launch(void* const* d_in, const int* in_sizes, int n_in,
                              void* d_out, int out_size, void* d_ws, size_t ws_size,
                              hipStream_t stream) {
  const float* x    = (const float*)d_in[0];
  const float* adj  = (const float*)d_in[1];
  const float* W    = (const float*)d_in[2];
  const float* a    = (const float*)d_in[3];
  const float* Wout = (const float*)d_in[4];
  const float* aout = (const float*)d_in[5];
  float* out = (float*)d_out;
  char* ws = (char*)d_ws;
  const size_t MB = 1048576;
  const size_t KB = 1024;

  unsigned int* bmask  = (unsigned int*)(ws);                    //  8 MB
  short* Whf           = (short*)(ws + 8 * MB);                  //  4 MB
  short* hcat          = (short*)(ws + 12 * MB);                 //  4 MB
  float* OpP           = (float*)(ws + 16 * MB);                 // 64 MB (8z x 4h x 8192 x 64)
  float* rsP           = (float*)(ws + 80 * MB);                 //  1 MB
  short* WB            = (short*)(ws + 81 * MB);                 // 256 KB
  float* f1i           = (float*)(ws + 81 * MB + 256 * KB);      // 128 KB
  float* f2i           = (float*)(ws + 81 * MB + 384 * KB);      // 128 KB
  float2* ACh          = (float2*)(ws + 81 * MB + 512 * KB);     // 256 KB
  unsigned int* BDh    = (unsigned int*)(ws + 81 * MB + 768 * KB); // 128 KB
  float* f1o           = (float*)(ws + 81 * MB + 896 * KB);      //  32 KB
  float* f2o           = (float*)(ws + 81 * MB + 928 * KB);      //  32 KB
  short* Wh2B          = (short*)(ws + 81 * MB + 960 * KB);      // 256 KB
  float* f2max         = (float*)(ws + 81 * MB + 1216 * KB);     //  16 B
  float* f2omax        = (float*)(ws + 81 * MB + 1216 * KB + 64);

  k_wprep<<<dim3(8, 4), 256, 0, stream>>>(W, WB);
  k_prep1<<<512, 256, 0, stream>>>(x, WB, a, Whf, f1i, f2i);
  k_rmax<<<NHEAD, 256, 0, stream>>>(f2i, f2max, NN, 4, 1);
  k_acbd<<<NN * NHEAD / 256, 256, 0, stream>>>(f1i, f2i, f2max, ACh, BDh);
  k_fuse1<<<dim3(NN / 64, ZSPLIT), 256, 0, stream>>>(adj, Whf, ACh, BDh, OpP, rsP, bmask);
  k_comb1<<<NN, 256, 0, stream>>>(OpP, rsP, hcat);
  k_gemm2<<<NN / 16, 256, 0, stream>>>(hcat, Wout, aout, Wh2B, f1o, f2o);
  k_rmax<<<1, 256, 0, stream>>>(f2o, f2omax, NN, 1, 0);
  k_attn2<<<NN, 256, 0, stream>>>(bmask, Wh2B, f1o, f2o, f2omax, out);
}

// Round 17
// 216.043 us; speedup vs baseline: 1.0314x; 1.0314x over previous
//
#include <hip/hip_runtime.h>
#include <hip/hip_bf16.h>

#define NN 8192
#define NFEAT 512
#define NHID 64
#define NCLASS 16
#define NHEAD 4
#define ALPHA 0.1f
#define ZSPLIT 4
#define JPB (NN / ZSPLIT)   // 2048 j per block (layer-1 dense)
#define DCH 128             // j per staged chunk (16 KB B-tile in LDS)
#define Z2 8
#define JPB2 (NN / Z2)      // 1024 j per block (layer-2 dense)

typedef short bf16x8 __attribute__((ext_vector_type(8)));
typedef float f32x4 __attribute__((ext_vector_type(4)));
typedef float fv4 __attribute__((ext_vector_type(4)));

__device__ __forceinline__ float lrelu(float x) { return fmaxf(x, ALPHA * x); }
__device__ __forceinline__ float elu(float x) { return x > 0.f ? x : __expf(x) - 1.f; }
__device__ __forceinline__ short f2b(float x) {
  union { __bf16 b; short s; } c; c.b = (__bf16)x; return c.s;
}
__device__ __forceinline__ float b2f(short x) {
  union { unsigned int u; float f; } c; c.u = ((unsigned int)(unsigned short)x) << 16; return c.f;
}

// ---------------- K0b: WB[h][d][k] = bf16(W[h][k][d]) ----------------
__global__ __launch_bounds__(256) void k_wprep(const float* __restrict__ W,
                                               short* __restrict__ WB) {
  __shared__ float t[64][65];
  const int h = blockIdx.y;
  const int k0 = blockIdx.x * 64;
  const int tid = threadIdx.x;
#pragma unroll
  for (int it = 0; it < 16; ++it) {
    const int r = it * 4 + (tid >> 6), c = tid & 63;
    t[r][c] = W[((size_t)h * NFEAT + k0 + r) * NHID + c];
  }
  __syncthreads();
#pragma unroll
  for (int it = 0; it < 16; ++it) {
    const int d = it * 4 + (tid >> 6), k = tid & 63;
    WB[((size_t)h * NHID + d) * NFEAT + k0 + k] = f2b(t[k][d]);
  }
}

// ---------------- K1: Wh = bf16(x) @ WB^T (MFMA); epilogue f1/f2 + Whf j-blocked ------
__global__ __launch_bounds__(256) void k_prep1(const float* __restrict__ x,
                                               const short* __restrict__ WB,
                                               const float* __restrict__ a,
                                               short* __restrict__ Whf,
                                               float* __restrict__ f1i,
                                               float* __restrict__ f2i) {
  __shared__ short tile[64][72];
  const int bid = blockIdx.x;
  const int h = bid >> 7;
  const int bm = (bid & 127) * 64;
  const int tid = threadIdx.x;
  const int wv = tid >> 6, lane = tid & 63;
  const int mr = lane & 15, kg = lane >> 4;
  f32x4 acc0 = {0.f, 0.f, 0.f, 0.f}, acc1 = acc0, acc2 = acc0, acc3 = acc0;
  const float* ap = x + (size_t)(bm + wv * 16 + mr) * NFEAT + kg * 8;
  const short* bp = WB + ((size_t)h * NHID + mr) * NFEAT + kg * 8;
#pragma unroll 2
  for (int k0 = 0; k0 < NFEAT; k0 += 32) {
    const float4 xa = *reinterpret_cast<const float4*>(ap);
    const float4 xb = *reinterpret_cast<const float4*>(ap + 4);
    bf16x8 af;
    af[0] = f2b(xa.x); af[1] = f2b(xa.y); af[2] = f2b(xa.z); af[3] = f2b(xa.w);
    af[4] = f2b(xb.x); af[5] = f2b(xb.y); af[6] = f2b(xb.z); af[7] = f2b(xb.w);
    const bf16x8 b0 = *reinterpret_cast<const bf16x8*>(bp);
    const bf16x8 b1 = *reinterpret_cast<const bf16x8*>(bp + 16 * NFEAT);
    const bf16x8 b2 = *reinterpret_cast<const bf16x8*>(bp + 32 * NFEAT);
    const bf16x8 b3 = *reinterpret_cast<const bf16x8*>(bp + 48 * NFEAT);
    acc0 = __builtin_amdgcn_mfma_f32_16x16x32_bf16(af, b0, acc0, 0, 0, 0);
    acc1 = __builtin_amdgcn_mfma_f32_16x16x32_bf16(af, b1, acc1, 0, 0, 0);
    acc2 = __builtin_amdgcn_mfma_f32_16x16x32_bf16(af, b2, acc2, 0, 0, 0);
    acc3 = __builtin_amdgcn_mfma_f32_16x16x32_bf16(af, b3, acc3, 0, 0, 0);
    ap += 32; bp += 32;
  }
  float a1v[4], a2v[4];
#pragma unroll
  for (int c = 0; c < 4; ++c) {
    a1v[c] = a[h * 128 + mr + c * 16];
    a2v[c] = a[h * 128 + 64 + mr + c * 16];
  }
#pragma unroll
  for (int q = 0; q < 4; ++q) {
    float s1 = acc0[q] * a1v[0] + acc1[q] * a1v[1] + acc2[q] * a1v[2] + acc3[q] * a1v[3];
    float s2 = acc0[q] * a2v[0] + acc1[q] * a2v[1] + acc2[q] * a2v[2] + acc3[q] * a2v[3];
#pragma unroll
    for (int off = 1; off < 16; off <<= 1) {
      s1 += __shfl_xor(s1, off);
      s2 += __shfl_xor(s2, off);
    }
    if (mr == 0) {
      const int i = bm + wv * 16 + kg * 4 + q;
      f1i[(size_t)i * 4 + h] = s1;
      f2i[(size_t)i * 4 + h] = s2;
    }
  }
#pragma unroll
  for (int q = 0; q < 4; ++q) {
    const int r = wv * 16 + kg * 4 + q;
    tile[r][mr +  0] = f2b(acc0[q]);
    tile[r][mr + 16] = f2b(acc1[q]);
    tile[r][mr + 32] = f2b(acc2[q]);
    tile[r][mr + 48] = f2b(acc3[q]);
  }
  __syncthreads();
#pragma unroll
  for (int it = 0; it < 2; ++it) {
    const int jbl = (tid >> 6) + it * 4;
    const int d = tid & 63;
    bf16x8 o;
#pragma unroll
    for (int jo = 0; jo < 8; ++jo) o[jo] = tile[jbl * 8 + jo][d];
    *reinterpret_cast<bf16x8*>(Whf +
        (((size_t)h * 1024 + (bm >> 3) + jbl) * 64 + d) * 8) = o;
  }
}

// ---------------- K2c: strided max reduce ----------------
__global__ __launch_bounds__(256) void k_rmax(const float* __restrict__ src,
                                              float* __restrict__ dst, int n, int stride,
                                              int boff) {
  const float* p = src + (size_t)blockIdx.x * boff;
  float m = -1e30f;
  for (int k = threadIdx.x; k < n; k += 256) m = fmaxf(m, p[(size_t)k * stride]);
#pragma unroll
  for (int off = 32; off; off >>= 1) m = fmaxf(m, __shfl_xor(m, off));
  __shared__ float sm[4];
  if ((threadIdx.x & 63) == 0) sm[threadIdx.x >> 6] = m;
  __syncthreads();
  if (threadIdx.x == 0) dst[blockIdx.x] = fmaxf(fmaxf(sm[0], sm[1]), fmaxf(sm[2], sm[3]));
}

// ---------------- K2d: per-node factor tables (layer 1) ----------------
__global__ __launch_bounds__(256) void k_acbd(const float* __restrict__ f1i,
                                              const float* __restrict__ f2i,
                                              const float* __restrict__ f2max,
                                              float2* __restrict__ ACh,
                                              unsigned int* __restrict__ BDh) {
  const int idx = blockIdx.x * 256 + threadIdx.x;
  const int i = idx & (NN - 1);
  const int h = idx >> 13;
  const float fm = f2max[h];
  const float f1 = f1i[(size_t)i * 4 + h];
  const float f2 = f2i[(size_t)i * 4 + h];
  const float s = f1 + fm;
  const float mrow = fmaxf(s, 0.1f * s);
  float2 ac;
  ac.x = __expf(s - mrow);
  ac.y = __expf(0.1f * s - mrow);
  ACh[(size_t)h * NN + i] = ac;
  const float t = f2 - fm;
  const unsigned int B = (unsigned short)f2b(__expf(t));
  const unsigned int D = (unsigned short)f2b(__expf(0.1f * t));
  BDh[(size_t)h * NN + i] = B | (D << 16);
}

// ---------------- K2e: per-node factor tables (layer 2) ----------------
__global__ __launch_bounds__(256) void k_acbd2(const float* __restrict__ f1o,
                                               const float* __restrict__ f2o,
                                               const float* __restrict__ f2omax,
                                               float2* __restrict__ AC2,
                                               unsigned int* __restrict__ BD2) {
  const int i = blockIdx.x * 256 + threadIdx.x;
  const float fm = f2omax[0];
  const float f1 = f1o[i];
  const float f2 = f2o[i];
  const float s = f1 + fm;
  const float mrow = fmaxf(s, 0.1f * s);
  float2 ac;
  ac.x = __expf(s - mrow);
  ac.y = __expf(0.1f * s - mrow);
  AC2[i] = ac;
  const float t = f2 - fm;
  const unsigned int B = (unsigned short)f2b(__expf(t));
  const unsigned int D = (unsigned short)f2b(__expf(0.1f * t));
  BD2[i] = B | (D << 16);
}

// ---------------- K3a: stream adj -> bitmask (pure HBM, nontemporal) ----------------
__global__ __launch_bounds__(256) void k_scan(const float* __restrict__ adj,
                                              unsigned int* __restrict__ bmask) {
  const fv4* a4 = reinterpret_cast<const fv4*>(adj);
  const int t0 = blockIdx.x * 256 + threadIdx.x;
#pragma unroll 4
  for (int it = 0; it < 32; ++it) {
    const int g = it * 524288 + t0;
    const fv4 v = __builtin_nontemporal_load(a4 + g);
    unsigned int nv = (unsigned int)((v.x > 0.f) | ((v.y > 0.f) << 1) |
                                     ((v.z > 0.f) << 2) | ((v.w > 0.f) << 3))
                      << ((threadIdx.x & 7) * 4);
    nv |= __shfl_xor(nv, 1);
    nv |= __shfl_xor(nv, 2);
    nv |= __shfl_xor(nv, 4);
    if ((threadIdx.x & 7) == 0) bmask[g >> 3] = nv;
  }
}

// ---------------- K3b: masked dense MFMA layer-1, K-split + LDS B-staging ----------------
__global__ __launch_bounds__(256) void k_dense1z(const unsigned int* __restrict__ bmask,
                                                 const short* __restrict__ Whf,
                                                 const float2* __restrict__ ACh,
                                                 const unsigned int* __restrict__ BDh,
                                                 float* __restrict__ OpP,
                                                 float* __restrict__ rsP) {
  __shared__ short sm_b[16 * 64 * 8];          // 16 KB B-tile
  __shared__ unsigned int sm_bd[DCH];
  __shared__ unsigned int sm_mask[64][5];
  const int i0 = blockIdx.x * 64;
  const int h = blockIdx.y;
  const int z = blockIdx.z;
  const int jb0 = z * JPB;
  const int tid = threadIdx.x;
  const int wv = tid >> 6, lane = tid & 63;
  const int mr = lane & 15, kg = lane >> 4;
  const int row_local = wv * 16 + mr;
  const float2 ac = ACh[(size_t)h * NN + i0 + row_local];
  f32x4 acc0 = {0.f, 0.f, 0.f, 0.f}, acc1 = acc0, acc2 = acc0, acc3 = acc0;
  float rs = 0.f;

  for (int jc = jb0; jc < jb0 + JPB; jc += DCH) {
    __syncthreads();
    {
      sm_mask[tid >> 2][tid & 3] =
          bmask[(size_t)(i0 + (tid >> 2)) * 256 + (jc >> 5) + (tid & 3)];
      if (tid < DCH) sm_bd[tid] = BDh[(size_t)h * NN + jc + tid];
      const uint4* src = reinterpret_cast<const uint4*>(
          Whf + ((size_t)h * 1024 + (jc >> 3)) * 512);
      uint4* dst = reinterpret_cast<uint4*>(sm_b);
#pragma unroll
      for (int u = 0; u < 4; ++u) dst[tid + u * 256] = src[tid + u * 256];
    }
    __syncthreads();
#pragma unroll
    for (int ks = 0; ks < DCH / 32; ++ks) {
      const int jl = ks * 32 + kg * 8;
      const uint4 bda = *reinterpret_cast<const uint4*>(&sm_bd[jl]);
      const uint4 bdb = *reinterpret_cast<const uint4*>(&sm_bd[jl + 4]);
      const unsigned int mb = (sm_mask[row_local][(jc - jb0) / 32 % 4 == 0 ? ks : ks] // placeholder no-op
                               >> 0);
      (void)mb;
      const unsigned int mbb = (sm_mask[row_local][ks] >> (kg * 8)) & 0xffu;
      bf16x8 af;
#define MKW(e, bdw)                                              \
      {                                                          \
        const float Bf = __uint_as_float((bdw) << 16);           \
        const float Df = __uint_as_float((bdw) & 0xffff0000u);   \
        float w_ = fmaxf(ac.x * Bf, ac.y * Df);                  \
        w_ = ((mbb >> (e)) & 1u) ? w_ : 0.f;                     \
        rs += w_;                                                \
        af[e] = f2b(w_);                                         \
      }
      MKW(0, bda.x) MKW(1, bda.y) MKW(2, bda.z) MKW(3, bda.w)
      MKW(4, bdb.x) MKW(5, bdb.y) MKW(6, bdb.z) MKW(7, bdb.w)
#undef MKW
      const short* wp = sm_b + ((size_t)(jl >> 3) * 64 + mr) * 8;
      const bf16x8 bf0 = *reinterpret_cast<const bf16x8*>(wp);
      const bf16x8 bf1 = *reinterpret_cast<const bf16x8*>(wp + 128);
      const bf16x8 bf2 = *reinterpret_cast<const bf16x8*>(wp + 256);
      const bf16x8 bf3 = *reinterpret_cast<const bf16x8*>(wp + 384);
      acc0 = __builtin_amdgcn_mfma_f32_16x16x32_bf16(af, bf0, acc0, 0, 0, 0);
      acc1 = __builtin_amdgcn_mfma_f32_16x16x32_bf16(af, bf1, acc1, 0, 0, 0);
      acc2 = __builtin_amdgcn_mfma_f32_16x16x32_bf16(af, bf2, acc2, 0, 0, 0);
      acc3 = __builtin_amdgcn_mfma_f32_16x16x32_bf16(af, bf3, acc3, 0, 0, 0);
    }
  }
  rs += __shfl_xor(rs, 16);
  rs += __shfl_xor(rs, 32);
  if (lane < 16)
    rsP[((size_t)z * NHEAD + h) * NN + i0 + wv * 16 + lane] = rs;
  float* op = OpP + (((size_t)z * NHEAD + h) * NN + i0) * 64;
#pragma unroll
  for (int q = 0; q < 4; ++q) {
    const int r = wv * 16 + kg * 4 + q;
    op[(size_t)r * 64 + mr +  0] = acc0[q];
    op[(size_t)r * 64 + mr + 16] = acc1[q];
    op[(size_t)r * 64 + mr + 32] = acc2[q];
    op[(size_t)r * 64 + mr + 48] = acc3[q];
  }
}

// ---------------- K3c: combine z-partials -> hcat bf16 ----------------
__global__ __launch_bounds__(256) void k_comb1(const float* __restrict__ OpP,
                                               const float* __restrict__ rsP,
                                               short* __restrict__ hcat) {
  const int idx = blockIdx.x * 256 + threadIdx.x;
  const int i = idx >> 8;
  const int hc = idx & 255;
  const int h = hc >> 6, d = hc & 63;
  float s = 0.f, rsum = 0.f;
#pragma unroll
  for (int z = 0; z < ZSPLIT; ++z) {
    s += OpP[(((size_t)z * NHEAD + h) * NN + i) * 64 + d];
    rsum += rsP[((size_t)z * NHEAD + h) * NN + i];
  }
  hcat[idx] = f2b(elu(s / rsum));
}

// ---------------- K4: Wh2f = (hcat @ W_out) bf16 j-blocked ; f1o/f2o ----------------
__global__ __launch_bounds__(256) void k_gemm2(const short* __restrict__ hcat,
                                               const float* __restrict__ Wout,
                                               const float* __restrict__ aout,
                                               short* __restrict__ Wh2f,
                                               float* __restrict__ f1o,
                                               float* __restrict__ f2o) {
  __shared__ float sW[NHEAD * NHID][NCLASS + 1];
  __shared__ float sh[16][NHEAD * NHID + 1];
  const int tid = threadIdx.x;
  const int r = tid >> 4, c = tid & 15;
  const int row = blockIdx.x * 16 + r;
  for (int u = tid; u < 256 * 16; u += 256) sW[u >> 4][u & 15] = Wout[u];
  for (int u = tid; u < 16 * 256; u += 256)
    sh[u >> 8][u & 255] = b2f(hcat[(size_t)(blockIdx.x * 16 + (u >> 8)) * 256 + (u & 255)]);
  __syncthreads();
  float acc = 0.f;
#pragma unroll 8
  for (int f = 0; f < 256; ++f) acc += sh[r][f] * sW[f][c];
  // j-blocked layout: Wh2f[((j>>3)*16 + c)*8 + (j&7)], j = row
  Wh2f[(((size_t)blockIdx.x * 2 + (r >> 3)) * 16 + c) * 8 + (r & 7)] = f2b(acc);
  float s1 = acc * aout[c];
  float s2 = acc * aout[NCLASS + c];
#pragma unroll
  for (int off = 8; off; off >>= 1) { s1 += __shfl_xor(s1, off); s2 += __shfl_xor(s2, off); }
  if (c == 0) { f1o[row] = s1; f2o[row] = s2; }
}

// ---------------- K5: masked dense MFMA layer-2, K-split ----------------
// grid (128, Z2): block = 64 rows x 1024 j; wave = 16-row M-sub; N=16, 1 MFMA / 32-j step.
__global__ __launch_bounds__(256) void k_dense2z(const unsigned int* __restrict__ bmask,
                                                 const short* __restrict__ Wh2f,
                                                 const float2* __restrict__ AC2,
                                                 const unsigned int* __restrict__ BD2,
                                                 float* __restrict__ Op2P,
                                                 float* __restrict__ rs2P) {
  __shared__ unsigned int sm_mask[64][33];
  const int i0 = blockIdx.x * 64;
  const int z = blockIdx.y;
  const int jb0 = z * JPB2;
  const int tid = threadIdx.x;
  // stage masks: 64 rows x 32 words
  {
    const int row = tid >> 2;
    const int w0 = (tid & 3) * 8;
#pragma unroll
    for (int u = 0; u < 8; ++u)
      sm_mask[row][w0 + u] = bmask[(size_t)(i0 + row) * 256 + (jb0 >> 5) + w0 + u];
  }
  __syncthreads();
  const int wv = tid >> 6, lane = tid & 63;
  const int mr = lane & 15, kg = lane >> 4;
  const int row_local = wv * 16 + mr;
  const float2 ac = AC2[i0 + row_local];
  f32x4 acc = {0.f, 0.f, 0.f, 0.f};
  float rs = 0.f;
  const unsigned int* bd = BD2 + jb0;
  const short* w2 = Wh2f + (size_t)(jb0 >> 3) * 128 + mr * 8;
#pragma unroll 2
  for (int ks = 0; ks < 32; ++ks) {
    const int jl = ks * 32 + kg * 8;
    const uint4 bda = *reinterpret_cast<const uint4*>(bd + jl);
    const uint4 bdb = *reinterpret_cast<const uint4*>(bd + jl + 4);
    const unsigned int mbb = (sm_mask[row_local][ks] >> (kg * 8)) & 0xffu;
    bf16x8 af;
#define MKW(e, bdw)                                              \
    {                                                            \
      const float Bf = __uint_as_float((bdw) << 16);             \
      const float Df = __uint_as_float((bdw) & 0xffff0000u);     \
      float w_ = fmaxf(ac.x * Bf, ac.y * Df);                    \
      w_ = ((mbb >> (e)) & 1u) ? w_ : 0.f;                       \
      rs += w_;                                                  \
      af[e] = f2b(w_);                                           \
    }
    MKW(0, bda.x) MKW(1, bda.y) MKW(2, bda.z) MKW(3, bda.w)
    MKW(4, bdb.x) MKW(5, bdb.y) MKW(6, bdb.z) MKW(7, bdb.w)
#undef MKW
    const bf16x8 bf = *reinterpret_cast<const bf16x8*>(w2 + (size_t)(jl >> 3) * 128);
    acc = __builtin_amdgcn_mfma_f32_16x16x32_bf16(af, bf, acc, 0, 0, 0);
  }
  rs += __shfl_xor(rs, 16);
  rs += __shfl_xor(rs, 32);
  if (lane < 16)
    rs2P[(size_t)z * NN + i0 + wv * 16 + lane] = rs;
  float* op = Op2P + ((size_t)z * NN + i0) * NCLASS;
#pragma unroll
  for (int q = 0; q < 4; ++q)
    op[(size_t)(wv * 16 + kg * 4 + q) * NCLASS + mr] = acc[q];
}

// ---------------- K5b: combine + ELU + log_softmax ----------------
__global__ __launch_bounds__(256) void k_comb2(const float* __restrict__ Op2P,
                                               const float* __restrict__ rs2P,
                                               float* __restrict__ out) {
  const int idx = blockIdx.x * 256 + threadIdx.x;
  const int i = idx >> 4;
  const int c = idx & 15;
  float s = 0.f, rsum = 0.f;
#pragma unroll
  for (int z = 0; z < Z2; ++z) {
    s += Op2P[((size_t)z * NN + i) * NCLASS + c];
    rsum += rs2P[(size_t)z * NN + i];
  }
  const float v = elu(s / rsum);
  float vm = v;
#pragma unroll
  for (int off = 8; off; off >>= 1) vm = fmaxf(vm, __shfl_xor(vm, off, 16));
  float ex = __expf(v - vm);
#pragma unroll
  for (int off = 8; off; off >>= 1) ex += __shfl_xor(ex, off, 16);
  out[idx] = v - vm - __logf(ex);
}

extern "C" void kernel_launch(void* const* d_in, const int* in_sizes, int n_in,
                              void* d_out, int out_size, void* d_ws, size_t ws_size,
                              hipStream_t stream) {
  const float* x    = (const float*)d_in[0];
  const float* adj  = (const float*)d_in[1];
  const float* W    = (const float*)d_in[2];
  const float* a    = (const float*)d_in[3];
  const float* Wout = (const float*)d_in[4];
  const float* aout = (const float*)d_in[5];
  float* out = (float*)d_out;
  char* ws = (char*)d_ws;
  const size_t MB = 1048576;
  const size_t KB = 1024;

  unsigned int* bmask  = (unsigned int*)(ws);                    //  8 MB
  short* Whf           = (short*)(ws + 8 * MB);                  //  4 MB
  short* hcat          = (short*)(ws + 12 * MB);                 //  4 MB
  float* OpP           = (float*)(ws + 16 * MB);                 // 32 MB
  float* rsP           = (float*)(ws + 48 * MB);                 // 512 KB
  float* Op2P          = (float*)(ws + 49 * MB);                 //  4 MB (8z x 8192 x 16)
  float* rs2P          = (float*)(ws + 53 * MB);                 // 256 KB
  short* WB            = (short*)(ws + 54 * MB);                 // 256 KB
  float* f1i           = (float*)(ws + 54 * MB + 256 * KB);      // 128 KB
  float* f2i           = (float*)(ws + 54 * MB + 384 * KB);      // 128 KB
  float2* ACh          = (float2*)(ws + 54 * MB + 512 * KB);     // 256 KB
  unsigned int* BDh    = (unsigned int*)(ws + 54 * MB + 768 * KB); // 128 KB
  float* f1o           = (float*)(ws + 54 * MB + 896 * KB);      //  32 KB
  float* f2o           = (float*)(ws + 54 * MB + 928 * KB);      //  32 KB
  short* Wh2f          = (short*)(ws + 54 * MB + 960 * KB);      // 256 KB
  float2* AC2          = (float2*)(ws + 54 * MB + 1216 * KB);    //  64 KB
  unsigned int* BD2    = (unsigned int*)(ws + 54 * MB + 1280 * KB); // 32 KB
  float* f2max         = (float*)(ws + 54 * MB + 1312 * KB);     //  16 B
  float* f2omax        = (float*)(ws + 54 * MB + 1312 * KB + 64);

  k_wprep<<<dim3(8, 4), 256, 0, stream>>>(W, WB);
  k_prep1<<<512, 256, 0, stream>>>(x, WB, a, Whf, f1i, f2i);
  k_rmax<<<NHEAD, 256, 0, stream>>>(f2i, f2max, NN, 4, 1);
  k_acbd<<<NN * NHEAD / 256, 256, 0, stream>>>(f1i, f2i, f2max, ACh, BDh);
  k_scan<<<2048, 256, 0, stream>>>(adj, bmask);
  k_dense1z<<<dim3(NN / 64, NHEAD, ZSPLIT), 256, 0, stream>>>(bmask, Whf, ACh, BDh, OpP, rsP);
  k_comb1<<<NN, 256, 0, stream>>>(OpP, rsP, hcat);
  k_gemm2<<<NN / 16, 256, 0, stream>>>(hcat, Wout, aout, Wh2f, f1o, f2o);
  k_rmax<<<1, 256, 0, stream>>>(f2o, f2omax, NN, 1, 0);
  k_acbd2<<<NN / 256, 256, 0, stream>>>(f1o, f2o, f2omax, AC2, BD2);
  k_dense2z<<<dim3(NN / 64, Z2), 256, 0, stream>>>(bmask, Wh2f, AC2, BD2, Op2P, rs2P);
  k_comb2<<<NN * NCLASS / 256, 256, 0, stream>>>(Op2P, rs2P, out);
}

// Round 18
// 212.384 us; speedup vs baseline: 1.0492x; 1.0172x over previous
//
#include <hip/hip_runtime.h>
#include <hip/hip_bf16.h>

#define NN 8192
#define NFEAT 512
#define NHID 64
#define NCLASS 16
#define NHEAD 4
#define ALPHA 0.1f
#define ZSPLIT 4
#define JPB (NN / ZSPLIT)   // 2048 j per block (layer-1 dense)
#define DCH 128             // j per staged chunk (16 KB B-tile in LDS)
#define Z2 8
#define JPB2 (NN / Z2)      // 1024 j per block (layer-2 dense)

typedef short bf16x8 __attribute__((ext_vector_type(8)));
typedef float f32x4 __attribute__((ext_vector_type(4)));
typedef float fv4 __attribute__((ext_vector_type(4)));

__device__ __forceinline__ float lrelu(float x) { return fmaxf(x, ALPHA * x); }
__device__ __forceinline__ float elu(float x) { return x > 0.f ? x : __expf(x) - 1.f; }
__device__ __forceinline__ short f2b(float x) {
  union { __bf16 b; short s; } c; c.b = (__bf16)x; return c.s;
}
__device__ __forceinline__ float b2f(short x) {
  union { unsigned int u; float f; } c; c.u = ((unsigned int)(unsigned short)x) << 16; return c.f;
}
// monotone float<->uint key for atomicMax
__device__ __forceinline__ unsigned int fkey(float f) {
  const unsigned int b = __float_as_uint(f);
  return (b & 0x80000000u) ? ~b : (b | 0x80000000u);
}
__device__ __forceinline__ float funkey(unsigned int k) {
  const unsigned int b = (k & 0x80000000u) ? (k & 0x7fffffffu) : ~k;
  return __uint_as_float(b);
}

// ---------------- K0b: WB[h][d][k] = bf16(W[h][k][d]) ----------------
__global__ __launch_bounds__(256) void k_wprep(const float* __restrict__ W,
                                               short* __restrict__ WB) {
  __shared__ float t[64][65];
  const int h = blockIdx.y;
  const int k0 = blockIdx.x * 64;
  const int tid = threadIdx.x;
#pragma unroll
  for (int it = 0; it < 16; ++it) {
    const int r = it * 4 + (tid >> 6), c = tid & 63;
    t[r][c] = W[((size_t)h * NFEAT + k0 + r) * NHID + c];
  }
  __syncthreads();
#pragma unroll
  for (int it = 0; it < 16; ++it) {
    const int d = it * 4 + (tid >> 6), k = tid & 63;
    WB[((size_t)h * NHID + d) * NFEAT + k0 + k] = f2b(t[k][d]);
  }
}

// ---------------- K1: Wh = bf16(x) @ WB^T (MFMA); epilogue f1/f2 + Whf + f2max atomic --
__global__ __launch_bounds__(256) void k_prep1(const float* __restrict__ x,
                                               const short* __restrict__ WB,
                                               const float* __restrict__ a,
                                               short* __restrict__ Whf,
                                               float* __restrict__ f1i,
                                               float* __restrict__ f2i,
                                               unsigned int* __restrict__ f2maxK) {
  __shared__ short tile[64][72];
  __shared__ float bmx[4];
  const int bid = blockIdx.x;
  const int h = bid >> 7;
  const int bm = (bid & 127) * 64;
  const int tid = threadIdx.x;
  const int wv = tid >> 6, lane = tid & 63;
  const int mr = lane & 15, kg = lane >> 4;
  f32x4 acc0 = {0.f, 0.f, 0.f, 0.f}, acc1 = acc0, acc2 = acc0, acc3 = acc0;
  const float* ap = x + (size_t)(bm + wv * 16 + mr) * NFEAT + kg * 8;
  const short* bp = WB + ((size_t)h * NHID + mr) * NFEAT + kg * 8;
#pragma unroll 2
  for (int k0 = 0; k0 < NFEAT; k0 += 32) {
    const float4 xa = *reinterpret_cast<const float4*>(ap);
    const float4 xb = *reinterpret_cast<const float4*>(ap + 4);
    bf16x8 af;
    af[0] = f2b(xa.x); af[1] = f2b(xa.y); af[2] = f2b(xa.z); af[3] = f2b(xa.w);
    af[4] = f2b(xb.x); af[5] = f2b(xb.y); af[6] = f2b(xb.z); af[7] = f2b(xb.w);
    const bf16x8 b0 = *reinterpret_cast<const bf16x8*>(bp);
    const bf16x8 b1 = *reinterpret_cast<const bf16x8*>(bp + 16 * NFEAT);
    const bf16x8 b2 = *reinterpret_cast<const bf16x8*>(bp + 32 * NFEAT);
    const bf16x8 b3 = *reinterpret_cast<const bf16x8*>(bp + 48 * NFEAT);
    acc0 = __builtin_amdgcn_mfma_f32_16x16x32_bf16(af, b0, acc0, 0, 0, 0);
    acc1 = __builtin_amdgcn_mfma_f32_16x16x32_bf16(af, b1, acc1, 0, 0, 0);
    acc2 = __builtin_amdgcn_mfma_f32_16x16x32_bf16(af, b2, acc2, 0, 0, 0);
    acc3 = __builtin_amdgcn_mfma_f32_16x16x32_bf16(af, b3, acc3, 0, 0, 0);
    ap += 32; bp += 32;
  }
  float a1v[4], a2v[4];
#pragma unroll
  for (int c = 0; c < 4; ++c) {
    a1v[c] = a[h * 128 + mr + c * 16];
    a2v[c] = a[h * 128 + 64 + mr + c * 16];
  }
  float m2 = -1e30f;
#pragma unroll
  for (int q = 0; q < 4; ++q) {
    float s1 = acc0[q] * a1v[0] + acc1[q] * a1v[1] + acc2[q] * a1v[2] + acc3[q] * a1v[3];
    float s2 = acc0[q] * a2v[0] + acc1[q] * a2v[1] + acc2[q] * a2v[2] + acc3[q] * a2v[3];
#pragma unroll
    for (int off = 1; off < 16; off <<= 1) {
      s1 += __shfl_xor(s1, off);
      s2 += __shfl_xor(s2, off);
    }
    m2 = fmaxf(m2, s2);
    if (mr == 0) {
      const int i = bm + wv * 16 + kg * 4 + q;
      f1i[(size_t)i * 4 + h] = s1;
      f2i[(size_t)i * 4 + h] = s2;
    }
  }
  m2 = fmaxf(m2, __shfl_xor(m2, 16));
  m2 = fmaxf(m2, __shfl_xor(m2, 32));
  if (lane == 0) bmx[wv] = m2;
#pragma unroll
  for (int q = 0; q < 4; ++q) {
    const int r = wv * 16 + kg * 4 + q;
    tile[r][mr +  0] = f2b(acc0[q]);
    tile[r][mr + 16] = f2b(acc1[q]);
    tile[r][mr + 32] = f2b(acc2[q]);
    tile[r][mr + 48] = f2b(acc3[q]);
  }
  __syncthreads();
  if (tid == 0)
    atomicMax(f2maxK + h, fkey(fmaxf(fmaxf(bmx[0], bmx[1]), fmaxf(bmx[2], bmx[3]))));
#pragma unroll
  for (int it = 0; it < 2; ++it) {
    const int jbl = (tid >> 6) + it * 4;
    const int d = tid & 63;
    bf16x8 o;
#pragma unroll
    for (int jo = 0; jo < 8; ++jo) o[jo] = tile[jbl * 8 + jo][d];
    *reinterpret_cast<bf16x8*>(Whf +
        (((size_t)h * 1024 + (bm >> 3) + jbl) * 64 + d) * 8) = o;
  }
}

// ---------------- K2d: per-node factor tables (layer 1) ----------------
__global__ __launch_bounds__(256) void k_acbd(const float* __restrict__ f1i,
                                              const float* __restrict__ f2i,
                                              const unsigned int* __restrict__ f2maxK,
                                              float2* __restrict__ ACh,
                                              unsigned int* __restrict__ BDh) {
  const int idx = blockIdx.x * 256 + threadIdx.x;
  const int i = idx & (NN - 1);
  const int h = idx >> 13;
  const float fm = funkey(f2maxK[h]);
  const float f1 = f1i[(size_t)i * 4 + h];
  const float f2 = f2i[(size_t)i * 4 + h];
  const float s = f1 + fm;
  const float mrow = fmaxf(s, 0.1f * s);
  float2 ac;
  ac.x = __expf(s - mrow);
  ac.y = __expf(0.1f * s - mrow);
  ACh[(size_t)h * NN + i] = ac;
  const float t = f2 - fm;
  const unsigned int B = (unsigned short)f2b(__expf(t));
  const unsigned int D = (unsigned short)f2b(__expf(0.1f * t));
  BDh[(size_t)h * NN + i] = B | (D << 16);
}

// ---------------- K2e: per-node factor tables (layer 2) ----------------
__global__ __launch_bounds__(256) void k_acbd2(const float* __restrict__ f1o,
                                               const float* __restrict__ f2o,
                                               const unsigned int* __restrict__ f2omaxK,
                                               float2* __restrict__ AC2,
                                               unsigned int* __restrict__ BD2) {
  const int i = blockIdx.x * 256 + threadIdx.x;
  const float fm = funkey(f2omaxK[0]);
  const float f1 = f1o[i];
  const float f2 = f2o[i];
  const float s = f1 + fm;
  const float mrow = fmaxf(s, 0.1f * s);
  float2 ac;
  ac.x = __expf(s - mrow);
  ac.y = __expf(0.1f * s - mrow);
  AC2[i] = ac;
  const float t = f2 - fm;
  const unsigned int B = (unsigned short)f2b(__expf(t));
  const unsigned int D = (unsigned short)f2b(__expf(0.1f * t));
  BD2[i] = B | (D << 16);
}

// ---------------- K3a: stream adj -> bitmask (pure HBM, nontemporal) ----------------
__global__ __launch_bounds__(256) void k_scan(const float* __restrict__ adj,
                                              unsigned int* __restrict__ bmask) {
  const fv4* a4 = reinterpret_cast<const fv4*>(adj);
  const int t0 = blockIdx.x * 256 + threadIdx.x;
#pragma unroll 4
  for (int it = 0; it < 32; ++it) {
    const int g = it * 524288 + t0;
    const fv4 v = __builtin_nontemporal_load(a4 + g);
    unsigned int nv = (unsigned int)((v.x > 0.f) | ((v.y > 0.f) << 1) |
                                     ((v.z > 0.f) << 2) | ((v.w > 0.f) << 3))
                      << ((threadIdx.x & 7) * 4);
    nv |= __shfl_xor(nv, 1);
    nv |= __shfl_xor(nv, 2);
    nv |= __shfl_xor(nv, 4);
    if ((threadIdx.x & 7) == 0) bmask[g >> 3] = nv;
  }
}

// ---------------- K3b: masked dense MFMA layer-1, K-split + T14 async LDS staging -----
// Per chunk: {barrier; ds_write regs (chunk c); issue global loads (chunk c+1); barrier;
// compute chunk c} — HBM/L2 latency of c+1 hides under compute of c.
__global__ __launch_bounds__(256) void k_dense1z(const unsigned int* __restrict__ bmask,
                                                 const short* __restrict__ Whf,
                                                 const float2* __restrict__ ACh,
                                                 const unsigned int* __restrict__ BDh,
                                                 float* __restrict__ OpP,
                                                 float* __restrict__ rsP) {
  __shared__ short sm_b[16 * 64 * 8];          // 16 KB B-tile
  __shared__ unsigned int sm_bd[DCH];
  __shared__ unsigned int sm_mask[64][5];
  const int i0 = blockIdx.x * 64;
  const int h = blockIdx.y;
  const int z = blockIdx.z;
  const int jb0 = z * JPB;
  const int tid = threadIdx.x;
  const int wv = tid >> 6, lane = tid & 63;
  const int mr = lane & 15, kg = lane >> 4;
  const int row_local = wv * 16 + mr;
  const float2 ac = ACh[(size_t)h * NN + i0 + row_local];
  f32x4 acc0 = {0.f, 0.f, 0.f, 0.f}, acc1 = acc0, acc2 = acc0, acc3 = acc0;
  float rs = 0.f;
  const int NCH = JPB / DCH;   // 16

  // prefetch registers
  unsigned int rM, rBD;
  uint4 rB0, rB1, rB2, rB3;
#define LOADR(jc)                                                              \
  {                                                                            \
    rM = bmask[(size_t)(i0 + (tid >> 2)) * 256 + ((jc) >> 5) + (tid & 3)];     \
    rBD = BDh[(size_t)h * NN + (jc) + (tid & (DCH - 1))];                      \
    const uint4* src_ = reinterpret_cast<const uint4*>(                       \
        Whf + ((size_t)h * 1024 + ((jc) >> 3)) * 512);                         \
    rB0 = src_[tid];                                                           \
    rB1 = src_[tid + 256];                                                     \
    rB2 = src_[tid + 512];                                                     \
    rB3 = src_[tid + 768];                                                     \
  }
  LOADR(jb0)
  for (int c = 0; c < NCH; ++c) {
    __syncthreads();   // previous chunk fully consumed
    sm_mask[tid >> 2][tid & 3] = rM;
    if (tid < DCH) sm_bd[tid] = rBD;
    {
      uint4* dst = reinterpret_cast<uint4*>(sm_b);
      dst[tid] = rB0; dst[tid + 256] = rB1; dst[tid + 512] = rB2; dst[tid + 768] = rB3;
    }
    if (c + 1 < NCH) LOADR(jb0 + (c + 1) * DCH)
    __syncthreads();
#pragma unroll
    for (int ks = 0; ks < DCH / 32; ++ks) {
      const int jl = ks * 32 + kg * 8;
      const uint4 bda = *reinterpret_cast<const uint4*>(&sm_bd[jl]);
      const uint4 bdb = *reinterpret_cast<const uint4*>(&sm_bd[jl + 4]);
      const unsigned int mbb = (sm_mask[row_local][ks] >> (kg * 8)) & 0xffu;
      bf16x8 af;
#define MKW(e, bdw)                                              \
      {                                                          \
        const float Bf = __uint_as_float((bdw) << 16);           \
        const float Df = __uint_as_float((bdw) & 0xffff0000u);   \
        float w_ = fmaxf(ac.x * Bf, ac.y * Df);                  \
        w_ = ((mbb >> (e)) & 1u) ? w_ : 0.f;                     \
        rs += w_;                                                \
        af[e] = f2b(w_);                                         \
      }
      MKW(0, bda.x) MKW(1, bda.y) MKW(2, bda.z) MKW(3, bda.w)
      MKW(4, bdb.x) MKW(5, bdb.y) MKW(6, bdb.z) MKW(7, bdb.w)
#undef MKW
      const short* wp = sm_b + ((size_t)(jl >> 3) * 64 + mr) * 8;
      const bf16x8 bf0 = *reinterpret_cast<const bf16x8*>(wp);
      const bf16x8 bf1 = *reinterpret_cast<const bf16x8*>(wp + 128);
      const bf16x8 bf2 = *reinterpret_cast<const bf16x8*>(wp + 256);
      const bf16x8 bf3 = *reinterpret_cast<const bf16x8*>(wp + 384);
      acc0 = __builtin_amdgcn_mfma_f32_16x16x32_bf16(af, bf0, acc0, 0, 0, 0);
      acc1 = __builtin_amdgcn_mfma_f32_16x16x32_bf16(af, bf1, acc1, 0, 0, 0);
      acc2 = __builtin_amdgcn_mfma_f32_16x16x32_bf16(af, bf2, acc2, 0, 0, 0);
      acc3 = __builtin_amdgcn_mfma_f32_16x16x32_bf16(af, bf3, acc3, 0, 0, 0);
    }
  }
#undef LOADR
  rs += __shfl_xor(rs, 16);
  rs += __shfl_xor(rs, 32);
  if (lane < 16)
    rsP[((size_t)z * NHEAD + h) * NN + i0 + wv * 16 + lane] = rs;
  float* op = OpP + (((size_t)z * NHEAD + h) * NN + i0) * 64;
#pragma unroll
  for (int q = 0; q < 4; ++q) {
    const int r = wv * 16 + kg * 4 + q;
    op[(size_t)r * 64 + mr +  0] = acc0[q];
    op[(size_t)r * 64 + mr + 16] = acc1[q];
    op[(size_t)r * 64 + mr + 32] = acc2[q];
    op[(size_t)r * 64 + mr + 48] = acc3[q];
  }
}

// ---------------- K3c: combine z-partials -> hcat bf16 ----------------
__global__ __launch_bounds__(256) void k_comb1(const float* __restrict__ OpP,
                                               const float* __restrict__ rsP,
                                               short* __restrict__ hcat) {
  const int idx = blockIdx.x * 256 + threadIdx.x;
  const int i = idx >> 8;
  const int hc = idx & 255;
  const int h = hc >> 6, d = hc & 63;
  float s = 0.f, rsum = 0.f;
#pragma unroll
  for (int z = 0; z < ZSPLIT; ++z) {
    s += OpP[(((size_t)z * NHEAD + h) * NN + i) * 64 + d];
    rsum += rsP[((size_t)z * NHEAD + h) * NN + i];
  }
  hcat[idx] = f2b(elu(s / rsum));
}

// ---------------- K4: Wh2f = (hcat @ W_out) bf16 j-blocked ; f1o/f2o + f2omax atomic --
__global__ __launch_bounds__(256) void k_gemm2(const short* __restrict__ hcat,
                                               const float* __restrict__ Wout,
                                               const float* __restrict__ aout,
                                               short* __restrict__ Wh2f,
                                               float* __restrict__ f1o,
                                               float* __restrict__ f2o,
                                               unsigned int* __restrict__ f2omaxK) {
  __shared__ float sW[NHEAD * NHID][NCLASS + 1];
  __shared__ float sh[16][NHEAD * NHID + 1];
  __shared__ float bmx[4];
  const int tid = threadIdx.x;
  const int r = tid >> 4, c = tid & 15;
  const int row = blockIdx.x * 16 + r;
  for (int u = tid; u < 256 * 16; u += 256) sW[u >> 4][u & 15] = Wout[u];
  for (int u = tid; u < 16 * 256; u += 256)
    sh[u >> 8][u & 255] = b2f(hcat[(size_t)(blockIdx.x * 16 + (u >> 8)) * 256 + (u & 255)]);
  __syncthreads();
  float acc = 0.f;
#pragma unroll 8
  for (int f = 0; f < 256; ++f) acc += sh[r][f] * sW[f][c];
  Wh2f[(((size_t)blockIdx.x * 2 + (r >> 3)) * 16 + c) * 8 + (r & 7)] = f2b(acc);
  float s1 = acc * aout[c];
  float s2 = acc * aout[NCLASS + c];
#pragma unroll
  for (int off = 8; off; off >>= 1) { s1 += __shfl_xor(s1, off); s2 += __shfl_xor(s2, off); }
  if (c == 0) { f1o[row] = s1; f2o[row] = s2; }
  float m2 = s2;
  m2 = fmaxf(m2, __shfl_xor(m2, 16));
  m2 = fmaxf(m2, __shfl_xor(m2, 32));
  if ((tid & 63) == 0) bmx[tid >> 6] = m2;
  __syncthreads();
  if (tid == 0)
    atomicMax(f2omaxK, fkey(fmaxf(fmaxf(bmx[0], bmx[1]), fmaxf(bmx[2], bmx[3]))));
}

// ---------------- K5: masked dense MFMA layer-2, K-split ----------------
__global__ __launch_bounds__(256) void k_dense2z(const unsigned int* __restrict__ bmask,
                                                 const short* __restrict__ Wh2f,
                                                 const float2* __restrict__ AC2,
                                                 const unsigned int* __restrict__ BD2,
                                                 float* __restrict__ Op2P,
                                                 float* __restrict__ rs2P) {
  __shared__ unsigned int sm_mask[64][33];
  const int i0 = blockIdx.x * 64;
  const int z = blockIdx.y;
  const int jb0 = z * JPB2;
  const int tid = threadIdx.x;
  {
    const int row = tid >> 2;
    const int w0 = (tid & 3) * 8;
#pragma unroll
    for (int u = 0; u < 8; ++u)
      sm_mask[row][w0 + u] = bmask[(size_t)(i0 + row) * 256 + (jb0 >> 5) + w0 + u];
  }
  __syncthreads();
  const int wv = tid >> 6, lane = tid & 63;
  const int mr = lane & 15, kg = lane >> 4;
  const int row_local = wv * 16 + mr;
  const float2 ac = AC2[i0 + row_local];
  f32x4 acc = {0.f, 0.f, 0.f, 0.f};
  float rs = 0.f;
  const unsigned int* bd = BD2 + jb0;
  const short* w2 = Wh2f + (size_t)(jb0 >> 3) * 128 + mr * 8;
#pragma unroll 2
  for (int ks = 0; ks < 32; ++ks) {
    const int jl = ks * 32 + kg * 8;
    const uint4 bda = *reinterpret_cast<const uint4*>(bd + jl);
    const uint4 bdb = *reinterpret_cast<const uint4*>(bd + jl + 4);
    const unsigned int mbb = (sm_mask[row_local][ks] >> (kg * 8)) & 0xffu;
    bf16x8 af;
#define MKW(e, bdw)                                              \
    {                                                            \
      const float Bf = __uint_as_float((bdw) << 16);             \
      const float Df = __uint_as_float((bdw) & 0xffff0000u);     \
      float w_ = fmaxf(ac.x * Bf, ac.y * Df);                    \
      w_ = ((mbb >> (e)) & 1u) ? w_ : 0.f;                       \
      rs += w_;                                                  \
      af[e] = f2b(w_);                                           \
    }
    MKW(0, bda.x) MKW(1, bda.y) MKW(2, bda.z) MKW(3, bda.w)
    MKW(4, bdb.x) MKW(5, bdb.y) MKW(6, bdb.z) MKW(7, bdb.w)
#undef MKW
    const bf16x8 bf = *reinterpret_cast<const bf16x8*>(w2 + (size_t)(jl >> 3) * 128);
    acc = __builtin_amdgcn_mfma_f32_16x16x32_bf16(af, bf, acc, 0, 0, 0);
  }
  rs += __shfl_xor(rs, 16);
  rs += __shfl_xor(rs, 32);
  if (lane < 16)
    rs2P[(size_t)z * NN + i0 + wv * 16 + lane] = rs;
  float* op = Op2P + ((size_t)z * NN + i0) * NCLASS;
#pragma unroll
  for (int q = 0; q < 4; ++q)
    op[(size_t)(wv * 16 + kg * 4 + q) * NCLASS + mr] = acc[q];
}

// ---------------- K5b: combine + ELU + log_softmax ----------------
__global__ __launch_bounds__(256) void k_comb2(const float* __restrict__ Op2P,
                                               const float* __restrict__ rs2P,
                                               float* __restrict__ out) {
  const int idx = blockIdx.x * 256 + threadIdx.x;
  const int i = idx >> 4;
  const int c = idx & 15;
  float s = 0.f, rsum = 0.f;
#pragma unroll
  for (int z = 0; z < Z2; ++z) {
    s += Op2P[((size_t)z * NN + i) * NCLASS + c];
    rsum += rs2P[(size_t)z * NN + i];
  }
  const float v = elu(s / rsum);
  float vm = v;
#pragma unroll
  for (int off = 8; off; off >>= 1) vm = fmaxf(vm, __shfl_xor(vm, off, 16));
  float ex = __expf(v - vm);
#pragma unroll
  for (int off = 8; off; off >>= 1) ex += __shfl_xor(ex, off, 16);
  out[idx] = v - vm - __logf(ex);
}

extern "C" void kernel_launch(void* const* d_in, const int* in_sizes, int n_in,
                              void* d_out, int out_size, void* d_ws, size_t ws_size,
                              hipStream_t stream) {
  const float* x    = (const float*)d_in[0];
  const float* adj  = (const float*)d_in[1];
  const float* W    = (const float*)d_in[2];
  const float* a    = (const float*)d_in[3];
  const float* Wout = (const float*)d_in[4];
  const float* aout = (const float*)d_in[5];
  float* out = (float*)d_out;
  char* ws = (char*)d_ws;
  const size_t MB = 1048576;
  const size_t KB = 1024;

  unsigned int* bmask  = (unsigned int*)(ws);                    //  8 MB
  short* Whf           = (short*)(ws + 8 * MB);                  //  4 MB
  short* hcat          = (short*)(ws + 12 * MB);                 //  4 MB
  float* OpP           = (float*)(ws + 16 * MB);                 // 32 MB
  float* rsP           = (float*)(ws + 48 * MB);                 // 512 KB
  float* Op2P          = (float*)(ws + 49 * MB);                 //  4 MB
  float* rs2P          = (float*)(ws + 53 * MB);                 // 256 KB
  short* WB            = (short*)(ws + 54 * MB);                 // 256 KB
  float* f1i           = (float*)(ws + 54 * MB + 256 * KB);      // 128 KB
  float* f2i           = (float*)(ws + 54 * MB + 384 * KB);      // 128 KB
  float2* ACh          = (float2*)(ws + 54 * MB + 512 * KB);     // 256 KB
  unsigned int* BDh    = (unsigned int*)(ws + 54 * MB + 768 * KB); // 128 KB
  float* f1o           = (float*)(ws + 54 * MB + 896 * KB);      //  32 KB
  float* f2o           = (float*)(ws + 54 * MB + 928 * KB);      //  32 KB
  short* Wh2f          = (short*)(ws + 54 * MB + 960 * KB);      // 256 KB
  float2* AC2          = (float2*)(ws + 54 * MB + 1216 * KB);    //  64 KB
  unsigned int* BD2    = (unsigned int*)(ws + 54 * MB + 1280 * KB); // 32 KB
  unsigned int* f2maxK = (unsigned int*)(ws + 54 * MB + 1312 * KB); // 4 keys + 1 key
  unsigned int* f2omaxK = f2maxK + 4;

  hipMemsetAsync(f2maxK, 0, 8 * sizeof(unsigned int), stream);
  k_wprep<<<dim3(8, 4), 256, 0, stream>>>(W, WB);
  k_prep1<<<512, 256, 0, stream>>>(x, WB, a, Whf, f1i, f2i, f2maxK);
  k_acbd<<<NN * NHEAD / 256, 256, 0, stream>>>(f1i, f2i, f2maxK, ACh, BDh);
  k_scan<<<2048, 256, 0, stream>>>(adj, bmask);
  k_dense1z<<<dim3(NN / 64, NHEAD, ZSPLIT), 256, 0, stream>>>(bmask, Whf, ACh, BDh, OpP, rsP);
  k_comb1<<<NN, 256, 0, stream>>>(OpP, rsP, hcat);
  k_gemm2<<<NN / 16, 256, 0, stream>>>(hcat, Wout, aout, Wh2f, f1o, f2o, f2omaxK);
  k_acbd2<<<NN / 256, 256, 0, stream>>>(f1o, f2o, f2omaxK, AC2, BD2);
  k_dense2z<<<dim3(NN / 64, Z2), 256, 0, stream>>>(bmask, Wh2f, AC2, BD2, Op2P, rs2P);
  k_comb2<<<NN * NCLASS / 256, 256, 0, stream>>>(Op2P, rs2P, out);
}